// Round 1
// 60.820 us; speedup vs baseline: 1.0082x; 1.0082x over previous
//
#include <hip/hip_runtime.h>

// MostPopularEncoder: B=32, L=2048, C=1000
// out[0] = hiddens [B, L, 2] (avg_delta, running_mode); out[1] = same flat data.
//
// avg_delta[b,t] = (ts[b,t] - ts[b,0]) / (t+1)   (cumsum of diffs telescopes)
// running mode  = lexicographic prefix-max over positions of key(t) =
//   (cnt[t] << 10) | (999 - lab[t]),  cnt[t] = occurrence rank of labels[t]
//   in labels[0..t] (1-based).  Ties resolve to smallest label == jnp.argmax.
//
// R4: critical-path trim over R3.
//  - Per-wave hist-row zeroing (wave w only touches hist[w] until Pass B),
//    which removes the zero->PassA barrier (3 barriers -> 2). In-wave LDS
//    write->read ordering covers the zero->read dependency, same as Pass A's
//    chunk0->chunk1 dependency already did.
//  - All global loads (ts0, ts[t0], ts[t1], both labels) hoisted to the top
//    so global latency hides under hist zero + ballot work instead of being
//    exposed on the epilogue tail.

#define SEQ_B 32
#define SEQ_L 2048
#define NCLASS 1000
#define NWAVE 16

__global__ __launch_bounds__(1024) void mpe_kernel(const float* __restrict__ ts,
                                                   const int* __restrict__ labels,
                                                   float* __restrict__ out) {
    __shared__ unsigned short hist[NWAVE][NCLASS];  // 32 KB; counts <= 2048 fit
    __shared__ unsigned int chunk_tot[2 * NWAVE];   // inclusive max per 64-chunk

    const int tid  = threadIdx.x;
    const int lane = tid & 63;
    const int w    = tid >> 6;
    const int b    = blockIdx.x;

    const int t0 = w * 128 + lane;
    const int t1 = t0 + 64;

    // ---- early global loads: issue before any LDS work so latency overlaps
    const float ts0v = ts[b * SEQ_L];
    const float tsa  = ts[b * SEQ_L + t0];
    const float tsb  = ts[b * SEQ_L + t1];
    const int   lab0 = labels[b * SEQ_L + t0];
    const int   lab1 = labels[b * SEQ_L + t1];

    // ---- zero own hist row only (500 dwords per wave); no barrier needed:
    // only this wave reads/writes hist[w] until the post-Pass-A barrier.
    {
        unsigned int* hw = (unsigned int*)hist[w];
#pragma unroll
        for (int i = 0; i < 8; ++i) {
            const int idx = lane + i * 64;
            if (idx < NCLASS / 2) hw[idx] = 0u;
        }
    }

    const unsigned long long lt_mask =
        (lane == 0) ? 0ull : (~0ull >> (64 - lane));

    // ---- Pass A: local occurrence ranks within this wave's two 64-chunks
    int lab_r[2] = {lab0, lab1};
    int cnt_r[2];
#pragma unroll
    for (int c = 0; c < 2; ++c) {
        const int lab = lab_r[c];

        unsigned long long eq = ~0ull;  // lanes with equal label (10 ballots)
#pragma unroll
        for (int bit = 0; bit < 10; ++bit) {
            unsigned long long bb = __ballot((lab >> bit) & 1);
            eq &= ((lab >> bit) & 1) ? bb : ~bb;
        }

        const int  rank    = __popcll(eq & lt_mask);         // earlier equal lanes
        const bool is_last = (((eq >> lane) >> 1) == 0ull);  // highest equal lane

        const int base = (int)hist[w][lab];  // equal-label lanes broadcast-read
        cnt_r[c] = base + rank + 1;          // local 1-based rank in segment
        if (is_last) hist[w][lab] = (unsigned short)(base + __popcll(eq));
    }
    __syncthreads();

    // ---- Pass B: add counts from earlier waves' segments, pack keys
    unsigned int key[2];
#pragma unroll
    for (int c = 0; c < 2; ++c) {
        int base = 0;
        for (int w2 = 0; w2 < w; ++w2) base += (int)hist[w2][lab_r[c]];
        const int cnt = cnt_r[c] + base;  // global 1-based occurrence rank
        key[c] = ((unsigned int)cnt << 10) | (unsigned int)(999 - lab_r[c]);
    }

    // ---- Pass C: in-place inclusive prefix-max, chunk-local then cross-chunk
    unsigned int scan[2] = {key[0], key[1]};
#pragma unroll
    for (int d = 1; d < 64; d <<= 1) {
        unsigned int o0 = (unsigned int)__shfl_up((int)scan[0], d, 64);
        unsigned int o1 = (unsigned int)__shfl_up((int)scan[1], d, 64);
        if (lane >= d) {
            if (o0 > scan[0]) scan[0] = o0;
            if (o1 > scan[1]) scan[1] = o1;
        }
    }
    if (lane == 63) {
        chunk_tot[2 * w]     = scan[0];
        chunk_tot[2 * w + 1] = scan[1];
    }
    __syncthreads();

    unsigned int pre0 = 0;  // max over chunks before chunk 2w
    for (int j = 0; j < 2 * w; ++j) {
        const unsigned int v = chunk_tot[j];
        if (v > pre0) pre0 = v;
    }
    const unsigned int c0t  = chunk_tot[2 * w];
    const unsigned int pre1 = pre0 > c0t ? pre0 : c0t;

    const unsigned int s0 = pre0 > scan[0] ? pre0 : scan[0];
    const unsigned int s1 = pre1 > scan[1] ? pre1 : scan[1];

    // ---- epilogue: avg_delta + mode, coalesced float2 stores (x2 outputs)
    const float a0 = (tsa - ts0v) / (float)(t0 + 1);
    const float a1 = (tsb - ts0v) / (float)(t1 + 1);

    const float2 o0 = make_float2(a0, (float)(999 - (int)(s0 & 1023u)));
    const float2 o1 = make_float2(a1, (float)(999 - (int)(s1 & 1023u)));

    float2* o2 = (float2*)out;
    o2[b * SEQ_L + t0] = o0;                      // output 0
    o2[b * SEQ_L + t1] = o1;
    o2[SEQ_B * SEQ_L + b * SEQ_L + t0] = o0;      // output 1 (same flat data)
    o2[SEQ_B * SEQ_L + b * SEQ_L + t1] = o1;
}

extern "C" void kernel_launch(void* const* d_in, const int* in_sizes, int n_in,
                              void* d_out, int out_size, void* d_ws, size_t ws_size,
                              hipStream_t stream) {
    const float* ts     = (const float*)d_in[0];
    const int*   labels = (const int*)d_in[1];
    float*       out    = (float*)d_out;

    mpe_kernel<<<dim3(SEQ_B), dim3(1024), 0, stream>>>(ts, labels, out);
}